// Round 1
// baseline (201357.666 us; speedup 1.0000x reference)
//
#include <hip/hip_runtime.h>
#include <math.h>

// ESN reservoir recurrence, persistent-kernel formulation.
// x_{s+1} = 0.3*x_s + 0.7*tanh(0.9*W @ x_s + win0 * u[s])
// out[d][s-1001] = x_{s+1}[d] for s >= 1001   (out is 900 x 29999, row-major)

#define DIM        900
#define T_TOTAL    31000
#define DISCARD_P1 1001          // DISCARD + 1
#define OUT_T      29999         // T_TOTAL - DISCARD - 1
#define NBLK       60
#define ROWS_PB    15            // DIM / NBLK
#define NTHREADS   256
#define SR         0.9f
#define LEAKY      0.7f

// Workspace layout (floats): [0..1023] xbuf0, [1024..2047] xbuf1, [2048] counter (u32)
#define XBUF_STRIDE 1024
#define CTR_OFF     2048

__global__ void esn_init_ws(float* ws) {
    int i = threadIdx.x + blockIdx.x * blockDim.x;
    if (i < 2 * XBUF_STRIDE) ws[i] = 0.0f;
    if (i == 0) ((unsigned int*)(ws + CTR_OFF))[0] = 0u;
}

__launch_bounds__(NTHREADS, 1)
__global__ void esn_persistent(const float* __restrict__ W,
                               const float* __restrict__ W_in,
                               const float* __restrict__ u,
                               float* __restrict__ out,
                               float* xbuf,                  // 2 * XBUF_STRIDE floats
                               unsigned int* counter)
{
    __shared__ float w_lds[ROWS_PB][DIM];   // 54000 B: 0.9*W rows for this block
    __shared__ float x_lds[DIM];            // 3600 B
    __shared__ float win0_lds[ROWS_PB];

    const int tid  = threadIdx.x;
    const int blk  = blockIdx.x;
    const int row0 = blk * ROWS_PB;

    // Prologue: stage this block's rows of 0.9*W into LDS (one-time).
    for (int i = tid; i < ROWS_PB * DIM; i += NTHREADS) {
        int r = i / DIM;
        int c = i - r * DIM;
        w_lds[r][c] = SR * W[(size_t)(row0 + r) * DIM + c];
    }
    if (tid < ROWS_PB) win0_lds[tid] = W_in[(size_t)(row0 + tid) * DIM];  // column 0
    __syncthreads();

    const int wave = tid >> 6;
    const int lane = tid & 63;

    for (int s = 0; s < T_TOTAL; ++s) {
        // ---- barrier: wait until all NBLK blocks finished step s-1 ----
        if (s > 0) {
            if (tid == 0) {
                const unsigned int target = (unsigned int)NBLK * (unsigned int)s;
                while (__hip_atomic_load(counter, __ATOMIC_RELAXED,
                                         __HIP_MEMORY_SCOPE_AGENT) < target) {
                    // spin; LLC round-trip dominates poll interval
                }
            }
            __syncthreads();
        }

        float* xin  = xbuf + (size_t)(s & 1) * XBUF_STRIDE;
        float* xout = xbuf + (size_t)((s + 1) & 1) * XBUF_STRIDE;

        // Stage current state into LDS via agent-scope (cache-bypassing) loads.
        for (int i = tid; i < DIM; i += NTHREADS) {
            x_lds[i] = __hip_atomic_load(xin + i, __ATOMIC_RELAXED,
                                         __HIP_MEMORY_SCOPE_AGENT);
        }
        const float ut = u[s];
        __syncthreads();

        // Each wave handles rows {wave, wave+4, wave+8, wave+12} (< ROWS_PB).
        for (int r = wave; r < ROWS_PB; r += 4) {
            float acc = 0.0f;
            for (int c = lane; c < DIM; c += 64)
                acc += w_lds[r][c] * x_lds[c];
            #pragma unroll
            for (int off = 32; off > 0; off >>= 1)
                acc += __shfl_down(acc, off, 64);
            if (lane == 0) {
                const int grow = row0 + r;
                const float xo = x_lds[grow];
                const float xn = (1.0f - LEAKY) * xo
                               + LEAKY * tanhf(acc + win0_lds[r] * ut);
                __hip_atomic_store(xout + grow, xn, __ATOMIC_RELAXED,
                                   __HIP_MEMORY_SCOPE_AGENT);
                if (s >= DISCARD_P1)
                    out[(size_t)grow * OUT_T + (s - DISCARD_P1)] = xn;
            }
        }

        // Drain all stores (compiler emits s_waitcnt vmcnt(0) before s_barrier),
        // then signal step completion.
        __syncthreads();
        if (tid == 0) {
            __hip_atomic_fetch_add(counter, 1u, __ATOMIC_RELAXED,
                                   __HIP_MEMORY_SCOPE_AGENT);
        }
    }
}

extern "C" void kernel_launch(void* const* d_in, const int* in_sizes, int n_in,
                              void* d_out, int out_size, void* d_ws, size_t ws_size,
                              hipStream_t stream) {
    const float* W    = (const float*)d_in[0];
    const float* W_in = (const float*)d_in[1];
    const float* u    = (const float*)d_in[2];
    float* out = (float*)d_out;
    float* ws  = (float*)d_ws;

    esn_init_ws<<<8, 256, 0, stream>>>(ws);
    esn_persistent<<<NBLK, NTHREADS, 0, stream>>>(
        W, W_in, u, out, ws, (unsigned int*)(ws + CTR_OFF));
}

// Round 2
// 141577.686 us; speedup vs baseline: 1.4222x; 1.4222x over previous
//
#include <hip/hip_runtime.h>
#include <math.h>

// ESN reservoir recurrence, persistent-kernel formulation.
// x_{s+1} = 0.3*x_s + 0.7*tanh(0.9*W @ x_s + win0 * u[s])
// out[d][s-1001] = x_{s+1}[d] for s >= 1001   (out is 900 x 29999, row-major)

#define DIM        900
#define T_TOTAL    31000
#define DISCARD_P1 1001          // DISCARD + 1
#define OUT_T      29999         // T_TOTAL - DISCARD - 1
#define NBLK       60
#define ROWS_PB    15            // DIM / NBLK
#define ROWS_PAD   16            // padded so every wave computes 4 rows branch-free
#define NTHREADS   256
#define SR         0.9f
#define LEAKY      0.7f

// Workspace layout (floats):
//   [0..1023]      xbuf0
//   [1024..2047]   xbuf1
//   [2048..3967]   flags: one u32 per block, 32-float (128 B) stride
#define XBUF_STRIDE 1024
#define FLAG_OFF    2048
#define FLAG_STRIDE 32
#define WS_INIT_N   4096

__global__ void esn_init_ws(float* ws) {
    int i = threadIdx.x + blockIdx.x * blockDim.x;
    if (i < WS_INIT_N) ws[i] = 0.0f;
}

__launch_bounds__(NTHREADS, 1)
__global__ void esn_persistent(const float* __restrict__ W,
                               const float* __restrict__ W_in,
                               const float* __restrict__ u,
                               float* __restrict__ out,
                               float* xbuf,                  // 2 * XBUF_STRIDE floats
                               unsigned int* flags)          // NBLK flags, FLAG_STRIDE u32 apart
{
    __shared__ float w_lds[ROWS_PAD][DIM];  // 57600 B: 0.9*W rows (row 15 = garbage pad)
    __shared__ float x_lds[DIM];            // 3600 B
    __shared__ float win0_lds[ROWS_PAD];

    const int tid  = threadIdx.x;
    const int blk  = blockIdx.x;
    const int row0 = blk * ROWS_PB;

    // Prologue: stage this block's rows of 0.9*W into LDS (one-time).
    for (int i = tid; i < ROWS_PB * DIM; i += NTHREADS) {
        int r = i / DIM;
        int c = i - r * DIM;
        w_lds[r][c] = SR * W[(size_t)(row0 + r) * DIM + c];
    }
    if (tid < ROWS_PB) win0_lds[tid] = W_in[(size_t)(row0 + tid) * DIM];  // column 0
    if (tid == ROWS_PB) win0_lds[ROWS_PB] = 0.0f;
    __syncthreads();

    const int wave  = tid >> 6;
    const int lane  = tid & 63;
    const int rbase = wave * 4;   // rows rbase..rbase+3 (row 15 is pad, never stored)

    for (int s = 0; s < T_TOTAL; ++s) {
        // ---- barrier: each of lanes 0..NBLK-1 (wave 0) spins on one block's flag ----
        if (s > 0) {
            if (tid < NBLK) {
                const unsigned int target = (unsigned int)s;
                while (__hip_atomic_load(flags + tid * FLAG_STRIDE, __ATOMIC_RELAXED,
                                         __HIP_MEMORY_SCOPE_AGENT) < target) {
                    // parallel spin: one vector load covers all 60 flags per round
                }
            }
            __syncthreads();
        }

        const float ut = u[s];
        float* xin  = xbuf + (size_t)(s & 1) * XBUF_STRIDE;
        float* xout = xbuf + (size_t)((s + 1) & 1) * XBUF_STRIDE;

        // Stage current state into LDS via agent-scope (L1-bypassing) loads.
        for (int i = tid; i < DIM; i += NTHREADS) {
            x_lds[i] = __hip_atomic_load(xin + i, __ATOMIC_RELAXED,
                                         __HIP_MEMORY_SCOPE_AGENT);
        }
        __syncthreads();

        // 4 rows per wave, one pass over x: 1 LDS x-read feeds 4 FMAs.
        float acc0 = 0.0f, acc1 = 0.0f, acc2 = 0.0f, acc3 = 0.0f;
        for (int c = lane; c < DIM; c += 64) {
            const float xv = x_lds[c];
            acc0 += w_lds[rbase + 0][c] * xv;
            acc1 += w_lds[rbase + 1][c] * xv;
            acc2 += w_lds[rbase + 2][c] * xv;
            acc3 += w_lds[rbase + 3][c] * xv;
        }
        // Butterfly-reduce all four accumulators (interleaved for ILP).
        #pragma unroll
        for (int off = 1; off < 64; off <<= 1) {
            acc0 += __shfl_xor(acc0, off, 64);
            acc1 += __shfl_xor(acc1, off, 64);
            acc2 += __shfl_xor(acc2, off, 64);
            acc3 += __shfl_xor(acc3, off, 64);
        }
        // Lanes 0..3 finish rows rbase..rbase+3 in parallel.
        if (lane < 4) {
            const int r = rbase + lane;
            if (r < ROWS_PB) {
                const float acc = (lane == 0) ? acc0 : (lane == 1) ? acc1
                                : (lane == 2) ? acc2 : acc3;
                const int grow = row0 + r;
                const float xn = (1.0f - LEAKY) * x_lds[grow]
                               + LEAKY * tanhf(acc + win0_lds[r] * ut);
                __hip_atomic_store(xout + grow, xn, __ATOMIC_RELAXED,
                                   __HIP_MEMORY_SCOPE_AGENT);
                if (s >= DISCARD_P1)
                    out[(size_t)grow * OUT_T + (s - DISCARD_P1)] = xn;
            }
        }

        // __syncthreads drains each wave's vmcnt -> xout stores are at the
        // coherence point before the flag store signals step completion.
        __syncthreads();
        if (tid == 0) {
            __hip_atomic_store(flags + blk * FLAG_STRIDE, (unsigned int)(s + 1),
                               __ATOMIC_RELEASE, __HIP_MEMORY_SCOPE_AGENT);
        }
    }
}

extern "C" void kernel_launch(void* const* d_in, const int* in_sizes, int n_in,
                              void* d_out, int out_size, void* d_ws, size_t ws_size,
                              hipStream_t stream) {
    const float* W    = (const float*)d_in[0];
    const float* W_in = (const float*)d_in[1];
    const float* u    = (const float*)d_in[2];
    float* out = (float*)d_out;
    float* ws  = (float*)d_ws;

    esn_init_ws<<<WS_INIT_N / 256, 256, 0, stream>>>(ws);
    esn_persistent<<<NBLK, NTHREADS, 0, stream>>>(
        W, W_in, u, out, ws, (unsigned int*)(ws + FLAG_OFF));
}